// Round 9
// baseline (219.398 us; speedup 1.0000x reference)
//
#include <hip/hip_runtime.h>

// SNN forward, round 13.
// convW: r10 base (1-deep forced A-prefetch, vmcnt(4), sched_barrier, no
// setprio — r11/r12 showed depth-2 and setprio both regress) + ONE variable:
// B-fragments prefetched one step ahead into registers via volatile
// ds_read_b64 asm, counted lgkmcnt(6) (never 0 until tail) + sched_barrier(0)
// per rule #18. The ~120cy LDS latency (2 exposed clusters/step in r10/r12)
// now hides under the current step's 384cy MFMA window. Volatile-asm program
// order enforces the schedule (r9: plain-HIP prefetch gets sunk).
// Operand values + MFMA order byte-identical -> u bit-exact.

typedef __attribute__((ext_vector_type(8))) _Float16 v8h;
typedef __attribute__((ext_vector_type(16))) float v16f;
typedef __attribute__((ext_vector_type(4))) unsigned int u32x4;
typedef _Float16 half_t;

#define NB 32
#define NC 64
#define NT 129
#define TIN 128
#define NM 40
#define MS8 72            // i8 LDS slot stride: 16 ml-lanes cover 32 banks
#define ROWB8 2952        // 41 slots * 72; slot 40 = zero column
#define SROWB8 2560       // global spike row bytes = 40*64 (i8)

// ---- weights -> MFMA A-fragments, order [tap12][cq4][ct2][hl2][lane64]x16B ----
// one launch covers both tables: blocks 0..47 -> w2/wf2, 48..95 -> w3/wf3
__global__ void prep_wfrag(const float* __restrict__ w2s, const float* __restrict__ w3s,
                           uint4* __restrict__ wf2o, uint4* __restrict__ wf3o) {
    int g = blockIdx.x;
    const float* w = (g < 48) ? w2s : w3s;
    uint4* wf = (g < 48) ? wf2o : wf3o;
    int tid = (g % 48) * 256 + threadIdx.x;     // 12288
    if (tid >= 12288) return;
    int lane = tid & 63;
    int rest = tid >> 6;
    int hl = rest & 1;
    int ct = (rest >> 1) & 1;
    int cq = (rest >> 2) & 3;
    int tap = rest >> 4;
    int kh = tap / 3, kw = tap % 3;
    int co = ct * 32 + (lane & 31);
    unsigned short o[8];
#pragma unroll
    for (int jj = 0; jj < 8; jj++) {
        int ci = cq * 16 + (lane >> 5) * 8 + jj;
        float wv = w[((co * 64 + ci) * 4 + kh) * 3 + kw];
        _Float16 hi = (_Float16)wv;
        _Float16 val = hl ? (_Float16)((wv - (float)hi) * 2048.0f) : hi;
        unsigned short us;
        __builtin_memcpy(&us, &val, 2);
        o[jj] = us;
    }
    uint4 r;
    __builtin_memcpy(&r, o, 16);
    wf[tid] = r;
}

// ---- conv1 (1->64ch, 4x3, pad(2,1)) + LIF1 -> i8 spikes ----
__global__ void conv1_lif1(const float* __restrict__ x, const float* __restrict__ w1,
                           unsigned char* __restrict__ s1) {
    const int mg = blockIdx.x;        // 0..9
    const int b = blockIdx.y;
    const int c = threadIdx.x & 63;
    const int ml = threadIdx.x >> 6;  // 0..3
    const int m = mg * 4 + ml;
    float w[4][3];
#pragma unroll
    for (int kh = 0; kh < 4; kh++)
#pragma unroll
        for (int kw = 0; kw < 3; kw++) w[kh][kw] = w1[(c * 4 + kh) * 3 + kw];
    const float* xb = x + (size_t)b * TIN * NM;

    float xw[12][3];                  // rows tb-2 .. tb+9
#pragma unroll
    for (int rr = 0; rr < 12; rr++)
#pragma unroll
        for (int kw = 0; kw < 3; kw++) xw[rr][kw] = 0.f;
#pragma unroll
    for (int rr = 2; rr < 4; rr++)
#pragma unroll
        for (int kw = 0; kw < 3; kw++) {
            int mc = m - 1 + kw;
            xw[rr][kw] = ((unsigned)mc < (unsigned)NM) ? xb[(rr - 2) * NM + mc] : 0.f;
        }

    unsigned char* orow = s1 + ((size_t)b * NT * NM + m) * 64 + c;
    float v = 0.f;
    const float TAUc = 10.0f / 7.0f;

    for (int tb = 0; tb < NT; tb += 8) {
#pragma unroll
        for (int q = 0; q < 8; q++) {
            int row = tb + 2 + q;
#pragma unroll
            for (int kw = 0; kw < 3; kw++) {
                int mc = m - 1 + kw;
                xw[4 + q][kw] = (row < TIN && (unsigned)mc < (unsigned)NM)
                                    ? xb[row * NM + mc] : 0.f;
            }
        }
        int kmax = (NT - tb) < 8 ? (NT - tb) : 8;
#pragma unroll
        for (int k = 0; k < 8; k++) {
            if (k < kmax) {
                float uacc = 0.f;
#pragma unroll
                for (int kh = 0; kh < 4; kh++)
#pragma unroll
                    for (int kw = 0; kw < 3; kw++) uacc += xw[k + kh][kw] * w[kh][kw];
                v = v + (uacc - v) / TAUc;
                orow[(size_t)(tb + k) * NM * 64] = (v >= 1.0f) ? 1 : 0;
                if (v >= 1.0f) v = 0.0f;
            }
        }
#pragma unroll
        for (int rr = 0; rr < 4; rr++)
#pragma unroll
            for (int kw = 0; kw < 3; kw++) xw[rr][kw] = xw[8 + rr][kw];
    }
}

// ---- exact i8{0,1} -> f16{0,1.0}: v_perm byte spread + *0x3C00 ----
__device__ inline v8h expand01(uint2 raw) {
    unsigned o0 = __builtin_amdgcn_perm(0u, raw.x, 0x04010400u) * 0x3C00u;
    unsigned o1 = __builtin_amdgcn_perm(0u, raw.x, 0x04030402u) * 0x3C00u;
    unsigned o2 = __builtin_amdgcn_perm(0u, raw.y, 0x04010400u) * 0x3C00u;
    unsigned o3 = __builtin_amdgcn_perm(0u, raw.y, 0x04030402u) * 0x3C00u;
    uint4 o = make_uint4(o0, o1, o2, o3);
    return __builtin_bit_cast(v8h, o);
}

// ---- MFMA conv 64->64, 4x3 dilated. 4 waves = 2 jj-pairs x 2 hl.
// A: inline-asm global_load_dwordx4, 1-step double buffer, vmcnt(4).
// B: inline-asm ds_read_b64, 1-step double buffer, lgkmcnt(6).
// sched_barrier(0) after each counted wait. Barrier-free K-loop. No setprio.
template <int DH, int PH, int DW, int PW, int RMOD>
__global__ __launch_bounds__(256, 2) void convW(const unsigned char* __restrict__ spk,
                                                const uint4* __restrict__ wfrag,
                                                float* __restrict__ u) {
    __shared__ uint2 ldsq[7 * ROWB8 / 8];       // 20,664 B
    char* lds = (char*)ldsq;
    const int tid = threadIdx.x;
    const int lane = tid & 63;
    const int wv = tid >> 6;                    // 0..3
    const int wp = wv >> 1;                     // 0..1 jj-pair
    const int hl = wv & 1;                      // 0=hi, 1=lo
    const int bx = blockIdx.x;
    const int b = blockIdx.y;
    int r, jj0;
    if (bx < 32) { r = bx % RMOD; jj0 = (bx / RMOD) * 4; }
    else         { r = 0;         jj0 = (32 / RMOD) * 4; }

    // ---- stage 7 lattice rows x 41 slots (slot 40 = zeros) x 8B chunks ----
    const char* spb = (const char*)spk + (size_t)b * NT * SROWB8;
#pragma unroll
    for (int k = 0; k < 9; k++) {
        int c = tid + k * 256;
        if (c < 2296) {
            int i = c / 328;
            int rem = c - i * 328;
            int s = rem >> 3;                   // m-slot 0..40
            int q = rem & 7;                    // 8B chunk
            int tg = r - PH + DH * (jj0 + i);
            uint2 val = make_uint2(0u, 0u);
            if ((unsigned)tg < (unsigned)NT && s < 40)
                val = *(const uint2*)(spb + ((size_t)tg * NM + s) * 64 + q * 8);
            *(uint2*)(lds + i * ROWB8 + s * MS8 + q * 8) = val;
        }
    }

    // ---- lane decode: pos-tile = 2jj x 16m ----
    const int pos = lane & 31;
    const int jl = pos >> 4;
    const int ml = pos & 15;
    const int hseg = lane >> 5;
    const int jj = jj0 + 2 * wp + jl;
    const int ldsrow = 2 * wp + jl;             // 0..3
    const int t = r + DH * jj;
    const int mtb[3] = {0, 16, 24};

    // B-read bases: OOB m -> zero column (slot 40); row step uniform ROWB8
    int P[3][3];
#pragma unroll
    for (int mt = 0; mt < 3; mt++)
#pragma unroll
        for (int kw = 0; kw < 3; kw++) {
            int md = mtb[mt] + ml + kw * DW - PW;
            int sel = ((unsigned)md < 40u) ? md : 40;
            P[mt][kw] = ldsrow * ROWB8 + sel * MS8 + hseg * 8;
        }

    v16f acc[3][2];                             // [m-tile][co-tile], one hl stream
#pragma unroll
    for (int a = 0; a < 3; a++)
#pragma unroll
        for (int c2 = 0; c2 < 2; c2++) acc[a][c2] = (v16f)(0.0f);

    // ---- forced A-prefetch (1-deep, r10) + forced B-prefetch (1-deep, new) ----
    // step s (0..23): tap = s>>1, cq pair = (s&1)*2 + {0,1}; A base = s*8192.
    unsigned voff0 = (unsigned)(hl * 1024 + lane * 16);
    unsigned voff1 = voff0 + 4096u;
    const char* wbp = (const char*)wfrag;       // SGPR base, +8192/step
    u32x4 Ab[2][4];                             // [parity][j*2+ct]
    uint2 Bb[2][6];                             // [parity][mt*2+j]

#define ISSUE4(PAR)                                                                   \
    {                                                                                 \
        asm volatile("global_load_dwordx4 %0, %1, %2"                                 \
                     : "=v"(Ab[PAR][0]) : "v"(voff0), "s"(wbp));                      \
        asm volatile("global_load_dwordx4 %0, %1, %2 offset:2048"                     \
                     : "=v"(Ab[PAR][1]) : "v"(voff0), "s"(wbp));                      \
        asm volatile("global_load_dwordx4 %0, %1, %2"                                 \
                     : "=v"(Ab[PAR][2]) : "v"(voff1), "s"(wbp));                      \
        asm volatile("global_load_dwordx4 %0, %1, %2 offset:2048"                     \
                     : "=v"(Ab[PAR][3]) : "v"(voff1), "s"(wbp));                      \
        wbp += 8192;                                                                  \
    }

// 6 ds_read_b64 for step S into buffer BUF: addresses P[mt][kw]+kh*ROWB8+cq*16
#define LOADB(S, BUF)                                                                 \
    {                                                                                 \
        constexpr int tp_ = (S) >> 1;                                                 \
        constexpr int kh_ = tp_ / 3, kw_ = tp_ % 3;                                   \
        constexpr int cq0_ = ((S) & 1) * 2;                                           \
        _Pragma("unroll")                                                             \
        for (int mt_ = 0; mt_ < 3; mt_++) {                                           \
            unsigned a_ = (unsigned)(P[mt_][kw_] + kh_ * ROWB8 + cq0_ * 16);          \
            asm volatile("ds_read_b64 %0, %1"                                         \
                         : "=v"(Bb[BUF][mt_ * 2 + 0]) : "v"(a_));                     \
            asm volatile("ds_read_b64 %0, %1 offset:16"                               \
                         : "=v"(Bb[BUF][mt_ * 2 + 1]) : "v"(a_));                     \
        }                                                                             \
    }

    ISSUE4(0);                                  // A for step 0 in flight over barrier
    __syncthreads();                            // staging visible (drains lgkm)
    LOADB(0, 0);                                // B for step 0

#pragma unroll
    for (int s = 0; s < 24; ++s) {
        if (s < 23) {
            if ((s & 1) == 0) ISSUE4(1) else ISSUE4(0);   // A for s+1
            asm volatile("s_waitcnt vmcnt(4)");            // A[s] landed
        } else {
            asm volatile("s_waitcnt vmcnt(0)");
        }
        __builtin_amdgcn_sched_barrier(0);      // rule #18 fence
        if (s < 23) {
            // B for s+1 (hides under this step's MFMAs); constexpr dispatch
            switch (s + 1) {
                case 1:  LOADB(1, 1);  break;  case 2:  LOADB(2, 0);  break;
                case 3:  LOADB(3, 1);  break;  case 4:  LOADB(4, 0);  break;
                case 5:  LOADB(5, 1);  break;  case 6:  LOADB(6, 0);  break;
                case 7:  LOADB(7, 1);  break;  case 8:  LOADB(8, 0);  break;
                case 9:  LOADB(9, 1);  break;  case 10: LOADB(10, 0); break;
                case 11: LOADB(11, 1); break;  case 12: LOADB(12, 0); break;
                case 13: LOADB(13, 1); break;  case 14: LOADB(14, 0); break;
                case 15: LOADB(15, 1); break;  case 16: LOADB(16, 0); break;
                case 17: LOADB(17, 1); break;  case 18: LOADB(18, 0); break;
                case 19: LOADB(19, 1); break;  case 20: LOADB(20, 0); break;
                case 21: LOADB(21, 1); break;  case 22: LOADB(22, 0); break;
                case 23: LOADB(23, 1); break;
            }
            asm volatile("s_waitcnt lgkmcnt(6)"); // B[s] ready; B[s+1] in flight
        } else {
            asm volatile("s_waitcnt lgkmcnt(0)");
        }
        __builtin_amdgcn_sched_barrier(0);      // rule #18 fence
        const int sb = s & 1;
#pragma unroll
        for (int j = 0; j < 2; ++j) {
            v8h B0 = expand01(Bb[sb][0 + j]);   // mt0, cq=(s&1)*2+j
            v8h B1 = expand01(Bb[sb][2 + j]);   // mt1
            v8h B2 = expand01(Bb[sb][4 + j]);   // mt2
            v8h A0 = __builtin_bit_cast(v8h, Ab[sb][j * 2 + 0]);
            v8h A1 = __builtin_bit_cast(v8h, Ab[sb][j * 2 + 1]);
            acc[0][0] = __builtin_amdgcn_mfma_f32_32x32x16_f16(A0, B0, acc[0][0], 0, 0, 0);
            acc[0][1] = __builtin_amdgcn_mfma_f32_32x32x16_f16(A1, B0, acc[0][1], 0, 0, 0);
            acc[1][0] = __builtin_amdgcn_mfma_f32_32x32x16_f16(A0, B1, acc[1][0], 0, 0, 0);
            acc[1][1] = __builtin_amdgcn_mfma_f32_32x32x16_f16(A1, B1, acc[1][1], 0, 0, 0);
            acc[2][0] = __builtin_amdgcn_mfma_f32_32x32x16_f16(A0, B2, acc[2][0], 0, 0, 0);
            acc[2][1] = __builtin_amdgcn_mfma_f32_32x32x16_f16(A1, B2, acc[2][1], 0, 0, 0);
        }
    }
#undef ISSUE4
#undef LOADB

    // ---- combine: lo wave -> LDS (reuse tile), hi wave adds+writes.
    // u = hi + lo/2048, identical arithmetic/order (bit-exact).
    const float invs = 1.0f / 2048.0f;
    float4* lred = (float4*)lds;                // 2 wp x 8 chunks x 64 lanes x 16B = 16KB
    __syncthreads();                            // all K-loop LDS reads done
#pragma unroll
    for (int mt = 0; mt < 3; mt++) {
        if (hl) {
#pragma unroll
            for (int ct = 0; ct < 2; ct++)
#pragma unroll
                for (int g = 0; g < 4; g++) {
                    float4 vv;
                    vv.x = acc[mt][ct][4 * g + 0];
                    vv.y = acc[mt][ct][4 * g + 1];
                    vv.z = acc[mt][ct][4 * g + 2];
                    vv.w = acc[mt][ct][4 * g + 3];
                    lred[(wp * 8 + ct * 4 + g) * 64 + lane] = vv;
                }
        }
        __syncthreads();
        if (!hl && t < NT) {
            int m = mtb[mt] + ml;
            float* base = u + ((size_t)(b * NT + t) * NM + m) * 64;
#pragma unroll
            for (int ct = 0; ct < 2; ct++)
#pragma unroll
                for (int g = 0; g < 4; g++) {
                    float4 lo = lred[(wp * 8 + ct * 4 + g) * 64 + lane];
                    int co = ct * 32 + 8 * g + 4 * hseg;
                    float4 val;
                    val.x = acc[mt][ct][4 * g + 0] + lo.x * invs;
                    val.y = acc[mt][ct][4 * g + 1] + lo.y * invs;
                    val.z = acc[mt][ct][4 * g + 2] + lo.z * invs;
                    val.w = acc[mt][ct][4 * g + 3] + lo.w * invs;
                    *(float4*)(base + co) = val;
                }
        }
        __syncthreads();
    }
}

// ---- LIF over T: u fp32 -> i8 spikes, unroll-16 ----
__global__ void lif_spikes(const float* __restrict__ u, unsigned char* __restrict__ s2) {
    int tid = blockIdx.x * 256 + threadIdx.x;   // 81920
    int b = tid / 2560;
    int cm = tid % 2560;
    const float* up = u + (size_t)b * NT * 2560 + cm;
    unsigned char* sp = s2 + (size_t)b * NT * 2560 + cm;
    float v = 0.f;
    const float TAUc = 10.0f / 7.0f;
    for (int tb = 0; tb < 128; tb += 16) {
        float uu[16];
#pragma unroll
        for (int k = 0; k < 16; k++) uu[k] = up[(size_t)(tb + k) * 2560];
#pragma unroll
        for (int k = 0; k < 16; k++) {
            v = v + (uu[k] - v) / TAUc;
            sp[(size_t)(tb + k) * 2560] = (v >= 1.0f) ? 1 : 0;
            if (v >= 1.0f) v = 0.f;
        }
    }
    float uu = up[(size_t)128 * 2560];
    v = v + (uu - v) / TAUc;
    sp[(size_t)128 * 2560] = (v >= 1.0f) ? 1 : 0;
}

// ---- LIF3: spike counts only (mean commutes with FC), unroll-16 ----
__global__ void lif_sum(const float* __restrict__ u, float* __restrict__ hsum) {
    int tid = blockIdx.x * 256 + threadIdx.x;   // 81920
    int b = tid / 2560;
    int cm = tid % 2560;                         // = m*64 + co
    int m = cm >> 6;
    int co = cm & 63;
    const float* up = u + (size_t)b * NT * 2560 + cm;
    float v = 0.f, cnt = 0.f;
    const float TAUc = 10.0f / 7.0f;
    for (int tb = 0; tb < 128; tb += 16) {
        float uu[16];
#pragma unroll
        for (int k = 0; k < 16; k++) uu[k] = up[(size_t)(tb + k) * 2560];
#pragma unroll
        for (int k = 0; k < 16; k++) {
            v = v + (uu[k] - v) / TAUc;
            if (v >= 1.0f) { cnt += 1.0f; v = 0.f; }
        }
    }
    float uu = up[(size_t)128 * 2560];
    v = v + (uu - v) / TAUc;
    if (v >= 1.0f) cnt += 1.0f;
    hsum[b * 2560 + co * NM + m] = cnt;          // feature index = c*40 + m
}

// ---- FC on counts: y[b,k] = bf[k] + (sum_cm cnt*wf[k,cm]) / 129 ----
__global__ void fc_out(const float* __restrict__ hsum, const float* __restrict__ wf,
                       const float* __restrict__ bfv, float* __restrict__ out) {
    int b = blockIdx.x;
    int tid = threadIdx.x;
    float p[12];
#pragma unroll
    for (int k = 0; k < 12; k++) p[k] = 0.0f;
    for (int cm = tid; cm < NC * NM; cm += 256) {
        float h = hsum[b * NC * NM + cm];
#pragma unroll
        for (int k = 0; k < 12; k++) p[k] += h * wf[k * (NC * NM) + cm];
    }
    __shared__ float red[12][4];
    int lane = tid & 63, w = tid >> 6;
#pragma unroll
    for (int k = 0; k < 12; k++) {
        float s = p[k];
#pragma unroll
        for (int off = 32; off > 0; off >>= 1) s += __shfl_down(s, off, 64);
        if (lane == 0) red[k][w] = s;
    }
    __syncthreads();
    if (tid < 12) {
        float s = red[tid][0] + red[tid][1] + red[tid][2] + red[tid][3];
        out[b * 12 + tid] = bfv[tid] + s / 129.0f;
    }
}

extern "C" void kernel_launch(void* const* d_in, const int* in_sizes, int n_in,
                              void* d_out, int out_size, void* d_ws, size_t ws_size,
                              hipStream_t stream) {
    const float* x  = (const float*)d_in[0];
    const float* w1 = (const float*)d_in[1];
    const float* w2 = (const float*)d_in[2];
    const float* w3 = (const float*)d_in[3];
    const float* wf = (const float*)d_in[4];
    const float* bf = (const float*)d_in[5];
    float* out = (float*)d_out;

    char* ws = (char*)d_ws;
    unsigned char* s1 = (unsigned char*)ws;          // 10,567,680 B (i8 spikes)
    unsigned char* s2 = (unsigned char*)(ws + 10567680); // 10,567,680 B
    float*  u   = (float*)(ws + 21135360);           // 42,270,720 B
    uint4*  wf2 = (uint4*)(ws + 63406080);           // 196,608 B
    uint4*  wf3 = (uint4*)(ws + 63602688);           // 196,608 B
    float* hsum = (float*)(ws + 63799296);           // 327,680 B (end ~64.1 MB)

    prep_wfrag<<<96, 256, 0, stream>>>(w2, w3, wf2, wf3);

    conv1_lif1<<<dim3(10, 32), 256, 0, stream>>>(x, w1, s1);

    convW<4, 6, 3, 3, 4><<<dim3(33, 32), 256, 0, stream>>>(s1, wf2, u);
    lif_spikes<<<320, 256, 0, stream>>>(u, s2);

    convW<16, 24, 9, 9, 16><<<dim3(33, 32), 256, 0, stream>>>(s2, wf3, u);
    lif_sum<<<320, 256, 0, stream>>>(u, hsum);

    fc_out<<<32, 256, 0, stream>>>(hsum, wf, bf, out);
}

// Round 10
// 201.651 us; speedup vs baseline: 1.0880x; 1.0880x over previous
//
#include <hip/hip_runtime.h>

// SNN forward, round 14.
// Consolidation: convW reverted to round-10 EXACTLY (1-deep forced inline-asm
// A-prefetch, vmcnt(4), sched_barrier(0), JIT ds_read B, no setprio) — the
// proven best; r11 (setprio), r12 (depth-2), r13 (B-prefetch) all regressed.
// Two low-risk additions outside the schedule:
//  (1) prep_wfrag merged into conv1_lif1's dispatch (independent work, one
//      fewer serialized launch);
//  (2) expand01's *0x3C00 via v_mul_u32_u24 (operand < 2^17 -> identical
//      bits; full-rate VOP2 with literal vs v_mul_lo_u32 VOP3).
// All arithmetic/order unchanged -> u bit-exact vs r10.

typedef __attribute__((ext_vector_type(8))) _Float16 v8h;
typedef __attribute__((ext_vector_type(16))) float v16f;
typedef __attribute__((ext_vector_type(4))) unsigned int u32x4;
typedef _Float16 half_t;

#define NB 32
#define NC 64
#define NT 129
#define TIN 128
#define NM 40
#define MS8 72            // i8 LDS slot stride: 16 ml-lanes cover 32 banks
#define ROWB8 2952        // 41 slots * 72; slot 40 = zero column
#define SROWB8 2560       // global spike row bytes = 40*64 (i8)

// ---- fused: blocks 0..95 build wfrag tables; blocks 96..415 run conv1+LIF1 ----
// wfrag order [tap12][cq4][ct2][hl2][lane64]x16B; A-frag (32x32x16 f16):
// lane holds A[co=ct*32+(lane&31)][ci=cq*16+(lane>>5)*8+jj]
__global__ void prep_conv1(const float* __restrict__ w2s, const float* __restrict__ w3s,
                           uint4* __restrict__ wf2o, uint4* __restrict__ wf3o,
                           const float* __restrict__ x, const float* __restrict__ w1,
                           unsigned char* __restrict__ s1) {
    const int bx = blockIdx.x;
    if (bx < 96) {
        // ---- prep_wfrag part ----
        const float* w = (bx < 48) ? w2s : w3s;
        uint4* wf = (bx < 48) ? wf2o : wf3o;
        int tid = (bx % 48) * 256 + threadIdx.x;    // 12288
        int lane = tid & 63;
        int rest = tid >> 6;
        int hl = rest & 1;
        int ct = (rest >> 1) & 1;
        int cq = (rest >> 2) & 3;
        int tap = rest >> 4;
        int kh = tap / 3, kw = tap % 3;
        int co = ct * 32 + (lane & 31);
        unsigned short o[8];
#pragma unroll
        for (int jj = 0; jj < 8; jj++) {
            int ci = cq * 16 + (lane >> 5) * 8 + jj;
            float wv = w[((co * 64 + ci) * 4 + kh) * 3 + kw];
            _Float16 hi = (_Float16)wv;
            _Float16 val = hl ? (_Float16)((wv - (float)hi) * 2048.0f) : hi;
            unsigned short us;
            __builtin_memcpy(&us, &val, 2);
            o[jj] = us;
        }
        uint4 r;
        __builtin_memcpy(&r, o, 16);
        wf[tid] = r;
        return;
    }
    // ---- conv1 (1->64ch, 4x3, pad(2,1)) + LIF1 -> i8 spikes ----
    const int idx = bx - 96;          // 0..319
    const int mg = idx % 10;          // 0..9
    const int b = idx / 10;           // 0..31
    const int c = threadIdx.x & 63;
    const int ml = threadIdx.x >> 6;  // 0..3
    const int m = mg * 4 + ml;
    float w[4][3];
#pragma unroll
    for (int kh = 0; kh < 4; kh++)
#pragma unroll
        for (int kw = 0; kw < 3; kw++) w[kh][kw] = w1[(c * 4 + kh) * 3 + kw];
    const float* xb = x + (size_t)b * TIN * NM;

    float xw[12][3];                  // rows tb-2 .. tb+9
#pragma unroll
    for (int rr = 0; rr < 12; rr++)
#pragma unroll
        for (int kw = 0; kw < 3; kw++) xw[rr][kw] = 0.f;
#pragma unroll
    for (int rr = 2; rr < 4; rr++)
#pragma unroll
        for (int kw = 0; kw < 3; kw++) {
            int mc = m - 1 + kw;
            xw[rr][kw] = ((unsigned)mc < (unsigned)NM) ? xb[(rr - 2) * NM + mc] : 0.f;
        }

    unsigned char* orow = s1 + ((size_t)b * NT * NM + m) * 64 + c;
    float v = 0.f;
    const float TAUc = 10.0f / 7.0f;

    for (int tb = 0; tb < NT; tb += 8) {
#pragma unroll
        for (int q = 0; q < 8; q++) {
            int row = tb + 2 + q;
#pragma unroll
            for (int kw = 0; kw < 3; kw++) {
                int mc = m - 1 + kw;
                xw[4 + q][kw] = (row < TIN && (unsigned)mc < (unsigned)NM)
                                    ? xb[row * NM + mc] : 0.f;
            }
        }
        int kmax = (NT - tb) < 8 ? (NT - tb) : 8;
#pragma unroll
        for (int k = 0; k < 8; k++) {
            if (k < kmax) {
                float uacc = 0.f;
#pragma unroll
                for (int kh = 0; kh < 4; kh++)
#pragma unroll
                    for (int kw = 0; kw < 3; kw++) uacc += xw[k + kh][kw] * w[kh][kw];
                v = v + (uacc - v) / TAUc;
                orow[(size_t)(tb + k) * NM * 64] = (v >= 1.0f) ? 1 : 0;
                if (v >= 1.0f) v = 0.0f;
            }
        }
#pragma unroll
        for (int rr = 0; rr < 4; rr++)
#pragma unroll
            for (int kw = 0; kw < 3; kw++) xw[rr][kw] = xw[8 + rr][kw];
    }
}

// ---- full-rate *0x3C00: operand < 2^17, bit-identical to 32b mul ----
__device__ inline unsigned mul3c00(unsigned x) {
    unsigned r;
    asm("v_mul_u32_u24 %0, 0x3C00, %1" : "=v"(r) : "v"(x));
    return r;
}

// ---- exact i8{0,1} -> f16{0,1.0}: v_perm byte spread + u24 mul ----
__device__ inline v8h expand01(uint2 raw) {
    unsigned o0 = mul3c00(__builtin_amdgcn_perm(0u, raw.x, 0x04010400u));
    unsigned o1 = mul3c00(__builtin_amdgcn_perm(0u, raw.x, 0x04030402u));
    unsigned o2 = mul3c00(__builtin_amdgcn_perm(0u, raw.y, 0x04010400u));
    unsigned o3 = mul3c00(__builtin_amdgcn_perm(0u, raw.y, 0x04030402u));
    uint4 o = make_uint4(o0, o1, o2, o3);
    return __builtin_bit_cast(v8h, o);
}

// ---- MFMA conv 64->64, 4x3 dilated. 4 waves = 2 jj-pairs x 2 hl.
// A stream: inline-asm global_load_dwordx4, half-tap double buffer,
// counted vmcnt(4) + sched_barrier(0). JIT ds_read B. Barrier-free K-loop.
// (round-10 schedule — the measured optimum; r11/r12/r13 variants all regress)
template <int DH, int PH, int DW, int PW, int RMOD>
__global__ __launch_bounds__(256, 2) void convW(const unsigned char* __restrict__ spk,
                                                const uint4* __restrict__ wfrag,
                                                float* __restrict__ u) {
    __shared__ uint2 ldsq[7 * ROWB8 / 8];       // 20,664 B
    char* lds = (char*)ldsq;
    const int tid = threadIdx.x;
    const int lane = tid & 63;
    const int wv = tid >> 6;                    // 0..3
    const int wp = wv >> 1;                     // 0..1 jj-pair
    const int hl = wv & 1;                      // 0=hi, 1=lo
    const int bx = blockIdx.x;
    const int b = blockIdx.y;
    int r, jj0;
    if (bx < 32) { r = bx % RMOD; jj0 = (bx / RMOD) * 4; }
    else         { r = 0;         jj0 = (32 / RMOD) * 4; }

    // ---- stage 7 lattice rows x 41 slots (slot 40 = zeros) x 8B chunks ----
    const char* spb = (const char*)spk + (size_t)b * NT * SROWB8;
#pragma unroll
    for (int k = 0; k < 9; k++) {
        int c = tid + k * 256;
        if (c < 2296) {
            int i = c / 328;
            int rem = c - i * 328;
            int s = rem >> 3;                   // m-slot 0..40
            int q = rem & 7;                    // 8B chunk
            int tg = r - PH + DH * (jj0 + i);
            uint2 val = make_uint2(0u, 0u);
            if ((unsigned)tg < (unsigned)NT && s < 40)
                val = *(const uint2*)(spb + ((size_t)tg * NM + s) * 64 + q * 8);
            *(uint2*)(lds + i * ROWB8 + s * MS8 + q * 8) = val;
        }
    }

    // ---- lane decode: pos-tile = 2jj x 16m ----
    const int pos = lane & 31;
    const int jl = pos >> 4;
    const int ml = pos & 15;
    const int hseg = lane >> 5;
    const int jj = jj0 + 2 * wp + jl;
    const int ldsrow = 2 * wp + jl;             // 0..3
    const int t = r + DH * jj;
    const int mtb[3] = {0, 16, 24};

    // B-read bases: OOB m -> zero column (slot 40); row step uniform ROWB8
    int P[3][3];
#pragma unroll
    for (int mt = 0; mt < 3; mt++)
#pragma unroll
        for (int kw = 0; kw < 3; kw++) {
            int md = mtb[mt] + ml + kw * DW - PW;
            int sel = ((unsigned)md < 40u) ? md : 40;
            P[mt][kw] = ldsrow * ROWB8 + sel * MS8 + hseg * 8;
        }

    v16f acc[3][2];                             // [m-tile][co-tile], one hl stream
#pragma unroll
    for (int a = 0; a < 3; a++)
#pragma unroll
        for (int c2 = 0; c2 < 2; c2++) acc[a][c2] = (v16f)(0.0f);

    // ---- forced A-prefetch state (round-10) ----
    // step s (0..23): tap = s>>1, cq pair = (s&1)*2 + {0,1}; byte base = s*8192.
    // voff_j = hl*1024 + lane*16 + j*4096; ct1 via offset:2048 immediate.
    unsigned voff0 = (unsigned)(hl * 1024 + lane * 16);
    unsigned voff1 = voff0 + 4096u;
    const char* wbp = (const char*)wfrag;       // SGPR base, +8192/step
    u32x4 Ab[2][4];                             // [parity][j*2+ct]

#define ISSUE4(PAR)                                                                   \
    {                                                                                 \
        asm volatile("global_load_dwordx4 %0, %1, %2"                                 \
                     : "=v"(Ab[PAR][0]) : "v"(voff0), "s"(wbp));                      \
        asm volatile("global_load_dwordx4 %0, %1, %2 offset:2048"                     \
                     : "=v"(Ab[PAR][1]) : "v"(voff0), "s"(wbp));                      \
        asm volatile("global_load_dwordx4 %0, %1, %2"                                 \
                     : "=v"(Ab[PAR][2]) : "v"(voff1), "s"(wbp));                      \
        asm volatile("global_load_dwordx4 %0, %1, %2 offset:2048"                     \
                     : "=v"(Ab[PAR][3]) : "v"(voff1), "s"(wbp));                      \
        wbp += 8192;                                                                  \
    }

    ISSUE4(0);                                  // step 0 in flight across the barrier
    __syncthreads();

#pragma unroll
    for (int s = 0; s < 24; ++s) {
        const int tap = s >> 1;
        const int kh = tap / 3, kw = tap % 3;
        if (s < 23) {
            if ((s & 1) == 0) ISSUE4(1) else ISSUE4(0);   // next step's buffer
            asm volatile("s_waitcnt vmcnt(4)");            // current step landed
        } else {
            asm volatile("s_waitcnt vmcnt(0)");
        }
        __builtin_amdgcn_sched_barrier(0);                 // rule #18 fence
#pragma unroll
        for (int j = 0; j < 2; ++j) {
            const int cq = (s & 1) * 2 + j;
            uint2 r0 = *(const uint2*)(lds + P[0][kw] + kh * ROWB8 + cq * 16);
            uint2 r1 = *(const uint2*)(lds + P[1][kw] + kh * ROWB8 + cq * 16);
            uint2 r2 = *(const uint2*)(lds + P[2][kw] + kh * ROWB8 + cq * 16);
            v8h B0 = expand01(r0);
            v8h B1 = expand01(r1);
            v8h B2 = expand01(r2);
            v8h A0 = __builtin_bit_cast(v8h, Ab[s & 1][j * 2 + 0]);
            v8h A1 = __builtin_bit_cast(v8h, Ab[s & 1][j * 2 + 1]);
            acc[0][0] = __builtin_amdgcn_mfma_f32_32x32x16_f16(A0, B0, acc[0][0], 0, 0, 0);
            acc[0][1] = __builtin_amdgcn_mfma_f32_32x32x16_f16(A1, B0, acc[0][1], 0, 0, 0);
            acc[1][0] = __builtin_amdgcn_mfma_f32_32x32x16_f16(A0, B1, acc[1][0], 0, 0, 0);
            acc[1][1] = __builtin_amdgcn_mfma_f32_32x32x16_f16(A1, B1, acc[1][1], 0, 0, 0);
            acc[2][0] = __builtin_amdgcn_mfma_f32_32x32x16_f16(A0, B2, acc[2][0], 0, 0, 0);
            acc[2][1] = __builtin_amdgcn_mfma_f32_32x32x16_f16(A1, B2, acc[2][1], 0, 0, 0);
        }
    }
#undef ISSUE4

    // ---- combine: lo wave -> LDS (reuse tile), hi wave adds+writes.
    // u = hi + lo/2048, identical arithmetic/order (bit-exact).
    const float invs = 1.0f / 2048.0f;
    float4* lred = (float4*)lds;                // 2 wp x 8 chunks x 64 lanes x 16B = 16KB
    __syncthreads();                            // all K-loop LDS reads done
#pragma unroll
    for (int mt = 0; mt < 3; mt++) {
        if (hl) {
#pragma unroll
            for (int ct = 0; ct < 2; ct++)
#pragma unroll
                for (int g = 0; g < 4; g++) {
                    float4 vv;
                    vv.x = acc[mt][ct][4 * g + 0];
                    vv.y = acc[mt][ct][4 * g + 1];
                    vv.z = acc[mt][ct][4 * g + 2];
                    vv.w = acc[mt][ct][4 * g + 3];
                    lred[(wp * 8 + ct * 4 + g) * 64 + lane] = vv;
                }
        }
        __syncthreads();
        if (!hl && t < NT) {
            int m = mtb[mt] + ml;
            float* base = u + ((size_t)(b * NT + t) * NM + m) * 64;
#pragma unroll
            for (int ct = 0; ct < 2; ct++)
#pragma unroll
                for (int g = 0; g < 4; g++) {
                    float4 lo = lred[(wp * 8 + ct * 4 + g) * 64 + lane];
                    int co = ct * 32 + 8 * g + 4 * hseg;
                    float4 val;
                    val.x = acc[mt][ct][4 * g + 0] + lo.x * invs;
                    val.y = acc[mt][ct][4 * g + 1] + lo.y * invs;
                    val.z = acc[mt][ct][4 * g + 2] + lo.z * invs;
                    val.w = acc[mt][ct][4 * g + 3] + lo.w * invs;
                    *(float4*)(base + co) = val;
                }
        }
        __syncthreads();
    }
}

// ---- LIF over T: u fp32 -> i8 spikes, unroll-16 ----
__global__ void lif_spikes(const float* __restrict__ u, unsigned char* __restrict__ s2) {
    int tid = blockIdx.x * 256 + threadIdx.x;   // 81920
    int b = tid / 2560;
    int cm = tid % 2560;
    const float* up = u + (size_t)b * NT * 2560 + cm;
    unsigned char* sp = s2 + (size_t)b * NT * 2560 + cm;
    float v = 0.f;
    const float TAUc = 10.0f / 7.0f;
    for (int tb = 0; tb < 128; tb += 16) {
        float uu[16];
#pragma unroll
        for (int k = 0; k < 16; k++) uu[k] = up[(size_t)(tb + k) * 2560];
#pragma unroll
        for (int k = 0; k < 16; k++) {
            v = v + (uu[k] - v) / TAUc;
            sp[(size_t)(tb + k) * 2560] = (v >= 1.0f) ? 1 : 0;
            if (v >= 1.0f) v = 0.f;
        }
    }
    float uu = up[(size_t)128 * 2560];
    v = v + (uu - v) / TAUc;
    sp[(size_t)128 * 2560] = (v >= 1.0f) ? 1 : 0;
}

// ---- LIF3: spike counts only (mean commutes with FC), unroll-16 ----
__global__ void lif_sum(const float* __restrict__ u, float* __restrict__ hsum) {
    int tid = blockIdx.x * 256 + threadIdx.x;   // 81920
    int b = tid / 2560;
    int cm = tid % 2560;                         // = m*64 + co
    int m = cm >> 6;
    int co = cm & 63;
    const float* up = u + (size_t)b * NT * 2560 + cm;
    float v = 0.f, cnt = 0.f;
    const float TAUc = 10.0f / 7.0f;
    for (int tb = 0; tb < 128; tb += 16) {
        float uu[16];
#pragma unroll
        for (int k = 0; k < 16; k++) uu[k] = up[(size_t)(tb + k) * 2560];
#pragma unroll
        for (int k = 0; k < 16; k++) {
            v = v + (uu[k] - v) / TAUc;
            if (v >= 1.0f) { cnt += 1.0f; v = 0.f; }
        }
    }
    float uu = up[(size_t)128 * 2560];
    v = v + (uu - v) / TAUc;
    if (v >= 1.0f) cnt += 1.0f;
    hsum[b * 2560 + co * NM + m] = cnt;          // feature index = c*40 + m
}

// ---- FC on counts: y[b,k] = bf[k] + (sum_cm cnt*wf[k,cm]) / 129 ----
__global__ void fc_out(const float* __restrict__ hsum, const float* __restrict__ wf,
                       const float* __restrict__ bfv, float* __restrict__ out) {
    int b = blockIdx.x;
    int tid = threadIdx.x;
    float p[12];
#pragma unroll
    for (int k = 0; k < 12; k++) p[k] = 0.0f;
    for (int cm = tid; cm < NC * NM; cm += 256) {
        float h = hsum[b * NC * NM + cm];
#pragma unroll
        for (int k = 0; k < 12; k++) p[k] += h * wf[k * (NC * NM) + cm];
    }
    __shared__ float red[12][4];
    int lane = tid & 63, w = tid >> 6;
#pragma unroll
    for (int k = 0; k < 12; k++) {
        float s = p[k];
#pragma unroll
        for (int off = 32; off > 0; off >>= 1) s += __shfl_down(s, off, 64);
        if (lane == 0) red[k][w] = s;
    }
    __syncthreads();
    if (tid < 12) {
        float s = red[tid][0] + red[tid][1] + red[tid][2] + red[tid][3];
        out[b * 12 + tid] = bfv[tid] + s / 129.0f;
    }
}

extern "C" void kernel_launch(void* const* d_in, const int* in_sizes, int n_in,
                              void* d_out, int out_size, void* d_ws, size_t ws_size,
                              hipStream_t stream) {
    const float* x  = (const float*)d_in[0];
    const float* w1 = (const float*)d_in[1];
    const float* w2 = (const float*)d_in[2];
    const float* w3 = (const float*)d_in[3];
    const float* wf = (const float*)d_in[4];
    const float* bf = (const float*)d_in[5];
    float* out = (float*)d_out;

    char* ws = (char*)d_ws;
    unsigned char* s1 = (unsigned char*)ws;          // 10,567,680 B (i8 spikes)
    unsigned char* s2 = (unsigned char*)(ws + 10567680); // 10,567,680 B
    float*  u   = (float*)(ws + 21135360);           // 42,270,720 B
    uint4*  wf2 = (uint4*)(ws + 63406080);           // 196,608 B
    uint4*  wf3 = (uint4*)(ws + 63602688);           // 196,608 B
    float* hsum = (float*)(ws + 63799296);           // 327,680 B (end ~64.1 MB)

    prep_conv1<<<416, 256, 0, stream>>>(w2, w3, wf2, wf3, x, w1, s1);

    convW<4, 6, 3, 3, 4><<<dim3(33, 32), 256, 0, stream>>>(s1, wf2, u);
    lif_spikes<<<320, 256, 0, stream>>>(u, s2);

    convW<16, 24, 9, 9, 16><<<dim3(33, 32), 256, 0, stream>>>(s2, wf3, u);
    lif_sum<<<320, 256, 0, stream>>>(u, hsum);

    fc_out<<<32, 256, 0, stream>>>(hsum, wf, bf, out);
}